// Round 1
// baseline (185.610 us; speedup 1.0000x reference)
//
#include <hip/hip_runtime.h>

// Problem constants (from reference setup_inputs)
constexpr int B  = 32;
constexpr int H  = 256;
constexpr int W  = 1216;
constexpr int HW = H * W;          // 311296 (divisible by 4)
constexpr int N  = B * HW;         // 9961472 elements in gt / weight_map
constexpr int NCHUNK = N / 4;      // 2490368 float4 chunks

// ws accumulator layout: 16 slots, each padded to 64 B (16 floats) so the
// 1024 block-level atomicAdds per slot serialize on independent cache lines.
//   slot j      (j=0..7): sum of err^2 for bin j+1
//   slot 8+j    (j=0..7): count for bin j+1
constexpr int ACC_STRIDE = 16;     // floats
constexpr int ACC_FLOATS = 16 * ACC_STRIDE;  // 1 KiB of ws

__global__ __launch_bounds__(256) void seg_mse_kernel(
    const float* __restrict__ pred,
    const float* __restrict__ gt,
    const int*   __restrict__ wm,
    float* __restrict__ acc)
{
    float sum[8] = {0.f, 0.f, 0.f, 0.f, 0.f, 0.f, 0.f, 0.f};
    float cnt[8] = {0.f, 0.f, 0.f, 0.f, 0.f, 0.f, 0.f, 0.f};

    const int tid    = blockIdx.x * blockDim.x + threadIdx.x;
    const int stride = gridDim.x * blockDim.x;

    const float4* __restrict__ gt4 = (const float4*)gt;
    const int4*   __restrict__ wm4 = (const int4*)wm;

    for (int c = tid; c < NCHUNK; c += stride) {
        const int i0 = c * 4;            // flat element index into gt/wm
        const int b  = i0 / HW;          // batch (magic-mul div by constant)
        // prediction[:,0,:,:] element i lives at i + b*HW (channel stride HW, 2 ch)
        const float4 p = *(const float4*)(pred + (i0 + b * HW));
        const float4 g = gt4[c];
        const int4   w = wm4[c];

        const float e0 = p.x - g.x, e1 = p.y - g.y;
        const float e2 = p.z - g.z, e3 = p.w - g.w;
        const float s0 = e0 * e0, s1 = e1 * e1, s2 = e2 * e2, s3 = e3 * e3;

#pragma unroll
        for (int j = 0; j < 8; ++j) {
            const int bin = j + 1;
            sum[j] += (w.x == bin) ? s0 : 0.f;
            cnt[j] += (w.x == bin) ? 1.f : 0.f;
            sum[j] += (w.y == bin) ? s1 : 0.f;
            cnt[j] += (w.y == bin) ? 1.f : 0.f;
            sum[j] += (w.z == bin) ? s2 : 0.f;
            cnt[j] += (w.z == bin) ? 1.f : 0.f;
            sum[j] += (w.w == bin) ? s3 : 0.f;
            cnt[j] += (w.w == bin) ? 1.f : 0.f;
        }
    }

    // wave (64-lane) butterfly reduction of all 16 partials
#pragma unroll
    for (int j = 0; j < 8; ++j) {
#pragma unroll
        for (int off = 32; off > 0; off >>= 1) {
            sum[j] += __shfl_down(sum[j], off);
            cnt[j] += __shfl_down(cnt[j], off);
        }
    }

    // cross-wave reduction in LDS (256 threads = 4 waves)
    __shared__ float lsum[4][8];
    __shared__ float lcnt[4][8];
    const int wave = threadIdx.x >> 6;
    const int lane = threadIdx.x & 63;
    if (lane == 0) {
#pragma unroll
        for (int j = 0; j < 8; ++j) {
            lsum[wave][j] = sum[j];
            lcnt[wave][j] = cnt[j];
        }
    }
    __syncthreads();

    if (threadIdx.x < 8) {
        const int j = threadIdx.x;
        const float t = lsum[0][j] + lsum[1][j] + lsum[2][j] + lsum[3][j];
        atomicAdd(&acc[j * ACC_STRIDE], t);
    } else if (threadIdx.x < 16) {
        const int j = threadIdx.x - 8;
        const float t = lcnt[0][j] + lcnt[1][j] + lcnt[2][j] + lcnt[3][j];
        atomicAdd(&acc[(8 + j) * ACC_STRIDE], t);
    }
}

__global__ void finalize_kernel(const float* __restrict__ acc,
                                float* __restrict__ out)
{
    if (threadIdx.x == 0) {
        float total = 0.f;
#pragma unroll
        for (int j = 0; j < 8; ++j) {
            const float s = acc[j * ACC_STRIDE];
            const float c = acc[(8 + j) * ACC_STRIDE];
            total += s / fmaxf(c, 1.f);
        }
        out[0] = total * (1.f / 8.f);
    }
}

extern "C" void kernel_launch(void* const* d_in, const int* in_sizes, int n_in,
                              void* d_out, int out_size, void* d_ws, size_t ws_size,
                              hipStream_t stream)
{
    const float* pred = (const float*)d_in[0];  // [32,2,256,1216] f32
    const float* gt   = (const float*)d_in[1];  // [32,1,256,1216] f32
    const int*   wm   = (const int*)d_in[2];    // [32,1,256,1216] i32
    float* acc = (float*)d_ws;

    // d_ws is poisoned to 0xAA before every launch — zero the accumulators.
    hipMemsetAsync(d_ws, 0, ACC_FLOATS * sizeof(float), stream);

    seg_mse_kernel<<<1024, 256, 0, stream>>>(pred, gt, wm, acc);
    finalize_kernel<<<1, 64, 0, stream>>>(acc, (float*)d_out);
}